// Round 1
// baseline (220.375 us; speedup 1.0000x reference)
//
#include <hip/hip_runtime.h>

// Problem constants (fixed by the reference): n=8, c=16, H=W=512.
#define NIMG 8
#define NCLS 16
#define HW   262144           // 512*512, = 2^18
#define NBIN (NIMG * NCLS)    // 128 (n,c) bins

// ---------------------------------------------------------------------------
// Main pass: per-pixel log-softmax gathered at target class, accumulated into
// per-(image,class) bins:  ws[0..127]   = sum of lp_t per (n,c)
//                          ws[128..255] = pixel count per (n,c)
// Each thread processes 4 consecutive pixels (float4 / int4 loads).
// ---------------------------------------------------------------------------
__global__ __launch_bounds__(256) void dwce_main(const float* __restrict__ pred,
                                                 const int* __restrict__ tgt,
                                                 float* __restrict__ ws) {
    __shared__ float s_sum[NBIN];
    __shared__ float s_cnt[NBIN];
    const int tid = threadIdx.x;
    if (tid < NBIN) { s_sum[tid] = 0.0f; s_cnt[tid] = 0.0f; }
    __syncthreads();

    const long long thread_id = (long long)blockIdx.x * blockDim.x + tid;
    const long long p0 = thread_id * 4;            // first of 4 pixels (all same image)
    const int n_img = (int)(p0 >> 18);             // p0 / HW
    const int hw    = (int)(p0 & (HW - 1));
    const float* base = pred + ((size_t)n_img * NCLS) * HW + hw;

    // Load all 16 channels for 4 pixels: coalesced 16B loads, stride HW floats.
    float4 v[NCLS];
#pragma unroll
    for (int c = 0; c < NCLS; ++c)
        v[c] = *(const float4*)(base + (size_t)c * HW);

    int4 t = *(const int4*)(tgt + p0);

    // componentwise max over channels
    float4 m = v[0];
#pragma unroll
    for (int c = 1; c < NCLS; ++c) {
        m.x = fmaxf(m.x, v[c].x);
        m.y = fmaxf(m.y, v[c].y);
        m.z = fmaxf(m.z, v[c].z);
        m.w = fmaxf(m.w, v[c].w);
    }
    // componentwise sum of exp(x - m), and gather x at target class
    float4 s = make_float4(0.f, 0.f, 0.f, 0.f);
    float xt0 = 0.f, xt1 = 0.f, xt2 = 0.f, xt3 = 0.f;
#pragma unroll
    for (int c = 0; c < NCLS; ++c) {
        s.x += __expf(v[c].x - m.x);
        s.y += __expf(v[c].y - m.y);
        s.z += __expf(v[c].z - m.z);
        s.w += __expf(v[c].w - m.w);
        if (t.x == c) xt0 = v[c].x;   // -> v_cndmask, no divergence
        if (t.y == c) xt1 = v[c].y;
        if (t.z == c) xt2 = v[c].z;
        if (t.w == c) xt3 = v[c].w;
    }
    const float lp0 = xt0 - (m.x + __logf(s.x));
    const float lp1 = xt1 - (m.y + __logf(s.y));
    const float lp2 = xt2 - (m.z + __logf(s.z));
    const float lp3 = xt3 - (m.w + __logf(s.w));

    const int b = n_img * NCLS;
    atomicAdd(&s_sum[b + t.x], lp0);
    atomicAdd(&s_sum[b + t.y], lp1);
    atomicAdd(&s_sum[b + t.z], lp2);
    atomicAdd(&s_sum[b + t.w], lp3);
    atomicAdd(&s_cnt[b + t.x], 1.0f);
    atomicAdd(&s_cnt[b + t.y], 1.0f);
    atomicAdd(&s_cnt[b + t.z], 1.0f);
    atomicAdd(&s_cnt[b + t.w], 1.0f);

    __syncthreads();
    if (tid < NBIN) {
        // HW fp32 global atomic add (device scope) — 2048 blocks x 128 bins
        unsafeAtomicAdd(&ws[tid],        s_sum[tid]);
        unsafeAtomicAdd(&ws[NBIN + tid], s_cnt[tid]);
    }
}

// ---------------------------------------------------------------------------
// Finalize: w_class from global counts, then loss = -mean_n(num[n]/den[n]).
// ---------------------------------------------------------------------------
__global__ __launch_bounds__(128) void dwce_final(const float* __restrict__ ws,
                                                  float* __restrict__ out) {
    __shared__ float sum[NBIN];
    __shared__ float cnt[NBIN];
    __shared__ float wcl[NCLS];
    __shared__ float ratio[NIMG];
    const int tid = threadIdx.x;
    sum[tid] = ws[tid];
    cnt[tid] = ws[NBIN + tid];
    __syncthreads();
    if (tid < NCLS) {
        float g = 0.f;
#pragma unroll
        for (int i = 0; i < NIMG; ++i) g += cnt[i * NCLS + tid];
        wcl[tid] = (g > 0.f) ? 1.0f / (g * (float)NCLS) : 0.0f;
    }
    __syncthreads();
    if (tid < NIMG) {
        float num = 0.f, den = 0.f;
#pragma unroll
        for (int c = 0; c < NCLS; ++c) {
            num += sum[tid * NCLS + c] * wcl[c];
            den += cnt[tid * NCLS + c] * wcl[c];
        }
        ratio[tid] = num / den;
    }
    __syncthreads();
    if (tid == 0) {
        float r = 0.f;
#pragma unroll
        for (int i = 0; i < NIMG; ++i) r += ratio[i];
        out[0] = -r * (1.0f / (float)NIMG);
    }
}

extern "C" void kernel_launch(void* const* d_in, const int* in_sizes, int n_in,
                              void* d_out, int out_size, void* d_ws, size_t ws_size,
                              hipStream_t stream) {
    const float* pred = (const float*)d_in[0];
    const int*   tgt  = (const int*)d_in[1];
    // d_in[2] (weights) is ignored by the reference.
    float* out = (float*)d_out;
    float* ws  = (float*)d_ws;

    // ws is re-poisoned to 0xAA before every launch — zero the 256 bins.
    hipMemsetAsync(ws, 0, 2 * NBIN * sizeof(float), stream);

    // 8*512*512 pixels / 4 per thread = 524288 threads = 2048 blocks of 256.
    const int total_threads = (NIMG * HW) / 4;
    dwce_main<<<total_threads / 256, 256, 0, stream>>>(pred, tgt, ws);
    dwce_final<<<1, 128, 0, stream>>>(ws, out);
}

// Round 2
// 208.766 us; speedup vs baseline: 1.0556x; 1.0556x over previous
//
#include <hip/hip_runtime.h>

// Problem constants (fixed by the reference): n=8, c=16, H=W=512.
#define NIMG 8
#define NCLS 16
#define HW   262144            // 512*512 = 2^18 pixels per image
#define NBLK 2048              // main-pass blocks; 256 blocks per image
// Each block: 256 threads x 4 pixels = 1024 consecutive pixels (one image).
// Workspace: partials[32][NBLK] floats = 256 KB (c-major for coalesced reduce).

// ---------------------------------------------------------------------------
// Main pass: chunked-online log-softmax (4 channels per chunk, register
// double-buffered prefetch), gather at target class, accumulate per-block
// (class-sum, class-count) in LDS, write non-atomic per-block partials.
// ---------------------------------------------------------------------------
__global__ __launch_bounds__(256) void dwce_main(const float* __restrict__ pred,
                                                 const int* __restrict__ tgt,
                                                 float* __restrict__ partials) {
    __shared__ float s_bin[32];   // [0..15] sum(lp_t) per class, [16..31] count
    const int tid = threadIdx.x;
    if (tid < 32) s_bin[tid] = 0.0f;
    __syncthreads();

    const int gid = blockIdx.x * 256 + tid;
    const long long p0 = (long long)gid * 4;       // 4 consecutive pixels, same image
    const int n_img = (int)(p0 >> 18);
    const int hw    = (int)(p0 & (HW - 1));
    const float* base = pred + (size_t)n_img * NCLS * HW + hw;

    const int4 t = *(const int4*)(tgt + p0);

    // register double-buffer: 4 channels (float4 each) per chunk
    float4 v[2][4];
#pragma unroll
    for (int j = 0; j < 4; ++j)
        v[0][j] = *(const float4*)(base + (size_t)j * HW);

    float4 m  = make_float4(-3.0e38f, -3.0e38f, -3.0e38f, -3.0e38f);
    float4 s  = make_float4(0.f, 0.f, 0.f, 0.f);
    float4 xt = make_float4(0.f, 0.f, 0.f, 0.f);

#pragma unroll
    for (int chunk = 0; chunk < 4; ++chunk) {
        const int cur = chunk & 1;
        if (chunk < 3) {                       // prefetch next chunk's channels
#pragma unroll
            for (int j = 0; j < 4; ++j)
                v[cur ^ 1][j] = *(const float4*)(base + (size_t)((chunk + 1) * 4 + j) * HW);
        }
        // chunk max (componentwise over the 4 channels)
        float4 mc = v[cur][0];
#pragma unroll
        for (int j = 1; j < 4; ++j) {
            mc.x = fmaxf(mc.x, v[cur][j].x);
            mc.y = fmaxf(mc.y, v[cur][j].y);
            mc.z = fmaxf(mc.z, v[cur][j].z);
            mc.w = fmaxf(mc.w, v[cur][j].w);
        }
        float4 mn;
        mn.x = fmaxf(m.x, mc.x);
        mn.y = fmaxf(m.y, mc.y);
        mn.z = fmaxf(m.z, mc.z);
        mn.w = fmaxf(m.w, mc.w);
        // rescale running sum (exp(-huge)=0 on first chunk)
        s.x *= __expf(m.x - mn.x);
        s.y *= __expf(m.y - mn.y);
        s.z *= __expf(m.z - mn.z);
        s.w *= __expf(m.w - mn.w);
#pragma unroll
        for (int j = 0; j < 4; ++j) {
            const int c = chunk * 4 + j;
            const float4 vv = v[cur][j];
            s.x += __expf(vv.x - mn.x);
            s.y += __expf(vv.y - mn.y);
            s.z += __expf(vv.z - mn.z);
            s.w += __expf(vv.w - mn.w);
            if (t.x == c) xt.x = vv.x;   // -> v_cndmask, no divergence
            if (t.y == c) xt.y = vv.y;
            if (t.z == c) xt.z = vv.z;
            if (t.w == c) xt.w = vv.w;
        }
        m = mn;
    }

    const float lp0 = xt.x - (m.x + __logf(s.x));
    const float lp1 = xt.y - (m.y + __logf(s.y));
    const float lp2 = xt.z - (m.z + __logf(s.z));
    const float lp3 = xt.w - (m.w + __logf(s.w));

    atomicAdd(&s_bin[t.x], lp0);
    atomicAdd(&s_bin[t.y], lp1);
    atomicAdd(&s_bin[t.z], lp2);
    atomicAdd(&s_bin[t.w], lp3);
    atomicAdd(&s_bin[16 + t.x], 1.0f);
    atomicAdd(&s_bin[16 + t.y], 1.0f);
    atomicAdd(&s_bin[16 + t.z], 1.0f);
    atomicAdd(&s_bin[16 + t.w], 1.0f);

    __syncthreads();
    if (tid < 32)   // non-atomic per-block partials, c-major: partials[c][block]
        partials[(size_t)tid * NBLK + blockIdx.x] = s_bin[tid];
}

// ---------------------------------------------------------------------------
// Finalize: reduce 2048 block-partials per bin, build w_class from global
// counts, compute -mean_n(num/den). Single block, 256 threads.
// Bin (c, n): partials[c*NBLK + n*256 .. +256) is contiguous (256 blocks/image).
// ---------------------------------------------------------------------------
__global__ __launch_bounds__(256) void dwce_final(const float* __restrict__ ws,
                                                  float* __restrict__ out) {
    __shared__ float tot[32][NIMG];   // [c(0..31)][n]
    __shared__ float wcl[NCLS];
    __shared__ float ratio[NIMG];
    const int tid = threadIdx.x;
    const int c = tid >> 3;           // 0..31
    const int n = tid & 7;            // 0..7

    const float4* p = (const float4*)(ws + (size_t)c * NBLK + n * 256);
    float4 a = make_float4(0.f, 0.f, 0.f, 0.f);
#pragma unroll 8
    for (int k = 0; k < 64; ++k) {
        float4 q = p[k];
        a.x += q.x; a.y += q.y; a.z += q.z; a.w += q.w;
    }
    tot[c][n] = (a.x + a.y) + (a.z + a.w);
    __syncthreads();

    if (tid < NCLS) {
        float g = 0.f;
#pragma unroll
        for (int i = 0; i < NIMG; ++i) g += tot[NCLS + tid][i];   // global class count
        wcl[tid] = (g > 0.f) ? 1.0f / (g * (float)NCLS) : 0.0f;
    }
    __syncthreads();
    if (tid < NIMG) {
        float num = 0.f, den = 0.f;
#pragma unroll
        for (int c2 = 0; c2 < NCLS; ++c2) {
            num += tot[c2][tid] * wcl[c2];
            den += tot[NCLS + c2][tid] * wcl[c2];
        }
        ratio[tid] = num / den;
    }
    __syncthreads();
    if (tid == 0) {
        float r = 0.f;
#pragma unroll
        for (int i = 0; i < NIMG; ++i) r += ratio[i];
        out[0] = -r * (1.0f / (float)NIMG);
    }
}

extern "C" void kernel_launch(void* const* d_in, const int* in_sizes, int n_in,
                              void* d_out, int out_size, void* d_ws, size_t ws_size,
                              hipStream_t stream) {
    const float* pred = (const float*)d_in[0];
    const int*   tgt  = (const int*)d_in[1];
    // d_in[2] (weights) is ignored by the reference.
    float* out = (float*)d_out;
    float* ws  = (float*)d_ws;   // 32*NBLK floats = 256 KB, fully overwritten

    dwce_main<<<NBLK, 256, 0, stream>>>(pred, tgt, ws);
    dwce_final<<<1, 256, 0, stream>>>(ws, out);
}